// Round 1
// baseline (343.024 us; speedup 1.0000x reference)
//
#include <hip/hip_runtime.h>

typedef unsigned short u16;
typedef unsigned int u32;

typedef __bf16 bf16x8 __attribute__((ext_vector_type(8)));
typedef float f32x4 __attribute__((ext_vector_type(4)));

__device__ inline u16 f2bf(float f) {
    u32 u = __float_as_uint(f);
    u32 r = u + 0x7fffu + ((u >> 16) & 1u);   // round-to-nearest-even
    return (u16)(r >> 16);
}

// ---- prep 1: cast y (fp32, M*K) -> bf16, 4 elems/thread ----
__global__ __launch_bounds__(256) void cast_y_kernel(const float* __restrict__ y,
                                                     u16* __restrict__ yb) {
    int i = blockIdx.x * 256 + threadIdx.x;
    float4 v = ((const float4*)y)[i];
    u32 a = (u32)f2bf(v.x) | ((u32)f2bf(v.y) << 16);
    u32 b = (u32)f2bf(v.z) | ((u32)f2bf(v.w) << 16);
    ((uint2*)yb)[i] = make_uint2(a, b);
}

// ---- prep 2: Wp[n][k] = bf16( rng[k]*w[k][n] + offset[k] ), 64x64 LDS transpose ----
__global__ __launch_bounds__(256) void make_wp_kernel(const float* __restrict__ w,
                                                      const float* __restrict__ rng,
                                                      const float* __restrict__ off,
                                                      u16* __restrict__ wp) {
    __shared__ u16 tile[64][65];          // +1 pad: transpose-read is 2-way conflict (free)
    const int n0 = (blockIdx.x & 63) * 64;
    const int k0 = (blockIdx.x >> 6) * 64;
    const int tx = threadIdx.x & 63;
    const int ty = threadIdx.x >> 6;      // 0..3
    #pragma unroll
    for (int i = 0; i < 16; ++i) {
        int r = ty * 16 + i;
        int k = k0 + r;
        float v = w[(size_t)k * 4096 + n0 + tx];      // coalesced 256B/wave
        tile[r][tx] = f2bf(rng[k] * v + off[k]);
    }
    __syncthreads();
    #pragma unroll
    for (int i = 0; i < 16; ++i) {
        int r = ty * 16 + i;
        wp[(size_t)(n0 + r) * 4096 + k0 + tx] = tile[tx][r];  // coalesced 128B/wave
    }
}

// ---- async global->LDS, 16B per lane, LDS dest = wave-uniform base + lane*16 ----
__device__ inline void gld16(const u16* g, u16* l) {
    __builtin_amdgcn_global_load_lds((const __attribute__((address_space(1))) void*)g,
                                     (__attribute__((address_space(3))) void*)l,
                                     16, 0, 0);
}

// ---- GEMM: out[m][n] = sum_k yb[m][k] * wp[n][k]  (both bf16, [*, K] row-major) ----
// 128x128 tile, BK=32, 256 threads = 4 waves (2x2), each wave 64x64 via 4x4 MFMA 16x16x32
__global__ __launch_bounds__(256) void gemm_kernel(const u16* __restrict__ yb,
                                                   const u16* __restrict__ wp,
                                                   float* __restrict__ out) {
    __shared__ u16 As[128 * 32];  // [m][k] dense, 8KB
    __shared__ u16 Bs[128 * 32];  // [n][k] dense, 8KB
    const int bm = blockIdx.y * 128;
    const int bn = blockIdx.x * 128;
    const int lane = threadIdx.x & 63;
    const int wv = threadIdx.x >> 6;
    const int wm = (wv >> 1) * 64;
    const int wn = (wv & 1) * 64;
    const int r = lane & 15;       // MFMA row/col within 16
    const int q = lane >> 4;       // quad 0..3

    // staging: 8KB per tile = 8 chunks of 1KB; wave wv stages chunks {2wv, 2wv+1} of each
    const int f0 = wv * 128 + lane;    // flat 16B-unit index, chunk c = 2wv
    const int f1 = f0 + 64;            // chunk c = 2wv+1
    const u16* gA0 = yb + (size_t)(bm + (f0 >> 2)) * 4096 + (f0 & 3) * 8;
    const u16* gA1 = yb + (size_t)(bm + (f1 >> 2)) * 4096 + (f1 & 3) * 8;
    const u16* gB0 = wp + (size_t)(bn + (f0 >> 2)) * 4096 + (f0 & 3) * 8;
    const u16* gB1 = wp + (size_t)(bn + (f1 >> 2)) * 4096 + (f1 & 3) * 8;
    u16* lA0 = &As[(wv * 2 + 0) * 512];   // wave-uniform LDS bases
    u16* lA1 = &As[(wv * 2 + 1) * 512];
    u16* lB0 = &Bs[(wv * 2 + 0) * 512];
    u16* lB1 = &Bs[(wv * 2 + 1) * 512];

    f32x4 acc[4][4] = {};

    for (int kt = 0; kt < 128; ++kt) {
        gld16(gA0, lA0);
        gld16(gA1, lA1);
        gld16(gB0, lB0);
        gld16(gB1, lB1);
        gA0 += 32; gA1 += 32; gB0 += 32; gB1 += 32;
        __syncthreads();   // drains vmcnt (global_load_lds) + barrier

        bf16x8 af[4], bfr[4];
        #pragma unroll
        for (int i = 0; i < 4; ++i)
            af[i] = *(const bf16x8*)&As[(wm + i * 16 + r) * 32 + q * 8];   // ds_read_b128
        #pragma unroll
        for (int i = 0; i < 4; ++i)
            bfr[i] = *(const bf16x8*)&Bs[(wn + i * 16 + r) * 32 + q * 8];
        #pragma unroll
        for (int i = 0; i < 4; ++i) {
            #pragma unroll
            for (int j = 0; j < 4; ++j)
                acc[i][j] = __builtin_amdgcn_mfma_f32_16x16x32_bf16(af[i], bfr[j], acc[i][j], 0, 0, 0);
        }
        __syncthreads();   // all waves done reading before next stage overwrites
    }

    // C/D layout: n = lane&15, m = (lane>>4)*4 + reg  [m89-verified]
    #pragma unroll
    for (int i = 0; i < 4; ++i) {
        const int gm = bm + wm + i * 16 + q * 4;
        #pragma unroll
        for (int j = 0; j < 4; ++j) {
            const int gn = bn + wn + j * 16 + r;
            float* op = out + (size_t)gm * 4096 + gn;
            #pragma unroll
            for (int rr = 0; rr < 4; ++rr)
                op[(size_t)rr * 4096] = acc[i][j][rr];
        }
    }
}

extern "C" void kernel_launch(void* const* d_in, const int* in_sizes, int n_in,
                              void* d_out, int out_size, void* d_ws, size_t ws_size,
                              hipStream_t stream) {
    const float* y   = (const float*)d_in[0];   // (B,T,C) = 2*2048*4096
    const float* w   = (const float*)d_in[1];   // (C,N)   = 4096*4096
    const float* rng = (const float*)d_in[2];   // (1,1,C) = 4096
    const float* off = (const float*)d_in[3];   // (C,)    = 4096
    float* out = (float*)d_out;                 // (B,T,N) fp32

    u16* yb = (u16*)d_ws;                       // 4096*4096 bf16 = 32MB
    u16* wp = yb + (size_t)4096 * 4096;         // 4096*4096 bf16 = 32MB (transposed [n][k])

    cast_y_kernel<<<16384, 256, 0, stream>>>(y, yb);
    make_wp_kernel<<<4096, 256, 0, stream>>>(w, rng, off, wp);
    dim3 grid(32, 32);
    gemm_kernel<<<grid, 256, 0, stream>>>(yb, wp, out);
}

// Round 2
// 338.029 us; speedup vs baseline: 1.0148x; 1.0148x over previous
//
#include <hip/hip_runtime.h>

typedef unsigned short u16;
typedef unsigned int u32;

typedef __bf16 bf16x8 __attribute__((ext_vector_type(8)));
typedef float f32x4 __attribute__((ext_vector_type(4)));

__device__ inline u16 f2bf(float f) {
    u32 u = __float_as_uint(f);
    u32 r = u + 0x7fffu + ((u >> 16) & 1u);   // round-to-nearest-even
    return (u16)(r >> 16);
}
__device__ inline u32 pack2(float a, float b) {
    return (u32)f2bf(a) | ((u32)f2bf(b) << 16);
}

// Swizzled bf16 storage (both yb and wp): 16B unit at p = row*512 + kt*4 + j
// holds logical k-chunk q = j ^ ((row>>1)&3) of k-tile kt (8 bf16 elements,
// k = kt*32 + q*8). This makes the GEMM's ds_read_b128 fragment reads
// exactly 2-way bank-aliased (free) instead of 8-way.

// ---- prep 1: cast y (fp32 [M][K]) -> swizzled bf16, one 16B unit/thread ----
__global__ __launch_bounds__(256) void cast_y_kernel(const float* __restrict__ y,
                                                     uint4* __restrict__ yb) {
    int p = blockIdx.x * 256 + threadIdx.x;   // 16B-unit index, [0, 4096*512)
    int row = p >> 9;
    int c = p & 511;
    int q = (c & 3) ^ ((row >> 1) & 3);
    int kstart = (c >> 2) * 32 + q * 8;
    const float* src = y + (size_t)row * 4096 + kstart;
    float4 v0 = ((const float4*)src)[0];
    float4 v1 = ((const float4*)src)[1];
    uint4 o;
    o.x = pack2(v0.x, v0.y);
    o.y = pack2(v0.z, v0.w);
    o.z = pack2(v1.x, v1.y);
    o.w = pack2(v1.z, v1.w);
    yb[p] = o;        // 16B/lane fully coalesced
}

// ---- prep 2: Wp[n][k] = bf16(rng[k]*w[k][n] + off[k]), transposed + swizzled ----
__global__ __launch_bounds__(256) void make_wp_kernel(const float* __restrict__ w,
                                                      const float* __restrict__ rng,
                                                      const float* __restrict__ off,
                                                      uint4* __restrict__ wp) {
    __shared__ u16 tile[64][72];              // [k_local][n_local], padded
    const int n0 = (blockIdx.x & 63) * 64;
    const int k0 = (blockIdx.x >> 6) * 64;
    const int tx = threadIdx.x & 63;
    const int ty = threadIdx.x >> 6;          // 0..3
    #pragma unroll
    for (int i = 0; i < 16; ++i) {
        int kk = ty * 16 + i;
        int k = k0 + kk;
        float v = w[(size_t)k * 4096 + n0 + tx];   // coalesced 256B/wave
        tile[kk][tx] = f2bf(rng[k] * v + off[k]);
    }
    __syncthreads();
    #pragma unroll
    for (int h = 0; h < 2; ++h) {
        int nl = (threadIdx.x >> 3) + h * 32;      // n_local 0..63
        int j = threadIdx.x & 7;                   // 16B unit within 64-k span
        int q = (j & 3) ^ ((nl >> 1) & 3);
        int kl = (j >> 2) * 32 + q * 8;            // k_local start of this unit
        uint4 o;
        o.x = (u32)tile[kl + 0][nl] | ((u32)tile[kl + 1][nl] << 16);
        o.y = (u32)tile[kl + 2][nl] | ((u32)tile[kl + 3][nl] << 16);
        o.z = (u32)tile[kl + 4][nl] | ((u32)tile[kl + 5][nl] << 16);
        o.w = (u32)tile[kl + 6][nl] | ((u32)tile[kl + 7][nl] << 16);
        wp[(size_t)(n0 + nl) * 512 + (k0 >> 3) + j] = o;   // 16B/lane coalesced
    }
}

// ---- async global->LDS, 16B per lane ----
__device__ inline void gld16(const u16* g, u16* l) {
    __builtin_amdgcn_global_load_lds((const __attribute__((address_space(1))) void*)g,
                                     (__attribute__((address_space(3))) void*)l,
                                     16, 0, 0);
}

// ---- GEMM: out[m][n] = sum_k yb[m][k] * wp[n][k], both swizzled bf16 [*,K] ----
// 128x128 tile, BK=32, 4 waves (2x2), each wave 64x64 via 4x4 MFMA 16x16x32
__global__ __launch_bounds__(256) void gemm_kernel(const u16* __restrict__ yb,
                                                   const u16* __restrict__ wp,
                                                   float* __restrict__ out) {
    __shared__ u16 As[128 * 32];  // flat copy of swizzled global, 8KB
    __shared__ u16 Bs[128 * 32];
    const int bm = blockIdx.y * 128;
    const int bn = blockIdx.x * 128;
    const int lane = threadIdx.x & 63;
    const int wv = threadIdx.x >> 6;
    const int wm = (wv >> 1) * 64;
    const int wn = (wv & 1) * 64;
    const int r = lane & 15;
    const int q = lane >> 4;
    const int qa = (q ^ ((lane >> 1) & 3)) * 8;   // swizzled k-chunk offset (u16)

    const int f0 = wv * 128 + lane;
    const int f1 = f0 + 64;
    const u16* gA0 = yb + (size_t)(bm + (f0 >> 2)) * 4096 + (f0 & 3) * 8;
    const u16* gA1 = yb + (size_t)(bm + (f1 >> 2)) * 4096 + (f1 & 3) * 8;
    const u16* gB0 = wp + (size_t)(bn + (f0 >> 2)) * 4096 + (f0 & 3) * 8;
    const u16* gB1 = wp + (size_t)(bn + (f1 >> 2)) * 4096 + (f1 & 3) * 8;
    u16* lA0 = &As[(wv * 2 + 0) * 512];
    u16* lA1 = &As[(wv * 2 + 1) * 512];
    u16* lB0 = &Bs[(wv * 2 + 0) * 512];
    u16* lB1 = &Bs[(wv * 2 + 1) * 512];

    f32x4 acc[4][4] = {};

    for (int kt = 0; kt < 128; ++kt) {
        gld16(gA0, lA0);
        gld16(gA1, lA1);
        gld16(gB0, lB0);
        gld16(gB1, lB1);
        gA0 += 32; gA1 += 32; gB0 += 32; gB1 += 32;
        __syncthreads();

        bf16x8 af[4], bfr[4];
        #pragma unroll
        for (int i = 0; i < 4; ++i)
            af[i] = *(const bf16x8*)&As[(wm + i * 16 + r) * 32 + qa];
        #pragma unroll
        for (int i = 0; i < 4; ++i)
            bfr[i] = *(const bf16x8*)&Bs[(wn + i * 16 + r) * 32 + qa];
        #pragma unroll
        for (int i = 0; i < 4; ++i) {
            #pragma unroll
            for (int j = 0; j < 4; ++j)
                acc[i][j] = __builtin_amdgcn_mfma_f32_16x16x32_bf16(af[i], bfr[j], acc[i][j], 0, 0, 0);
        }
        __syncthreads();
    }

    // C/D layout: n = lane&15, m = (lane>>4)*4 + reg
    #pragma unroll
    for (int i = 0; i < 4; ++i) {
        const int gm = bm + wm + i * 16 + q * 4;
        #pragma unroll
        for (int j = 0; j < 4; ++j) {
            const int gn = bn + wn + j * 16 + r;
            float* op = out + (size_t)gm * 4096 + gn;
            #pragma unroll
            for (int rr = 0; rr < 4; ++rr)
                op[(size_t)rr * 4096] = acc[i][j][rr];
        }
    }
}

extern "C" void kernel_launch(void* const* d_in, const int* in_sizes, int n_in,
                              void* d_out, int out_size, void* d_ws, size_t ws_size,
                              hipStream_t stream) {
    const float* y   = (const float*)d_in[0];   // (B,T,C) = 2*2048*4096
    const float* w   = (const float*)d_in[1];   // (C,N)   = 4096*4096
    const float* rng = (const float*)d_in[2];   // (1,1,C) = 4096
    const float* off = (const float*)d_in[3];   // (C,)    = 4096
    float* out = (float*)d_out;                 // (B,T,N) fp32

    u16* yb = (u16*)d_ws;                       // 32MB swizzled bf16 [m][k]
    u16* wp = yb + (size_t)4096 * 4096;         // 32MB swizzled bf16 [n][k]

    cast_y_kernel<<<8192, 256, 0, stream>>>(y, (uint4*)yb);
    make_wp_kernel<<<4096, 256, 0, stream>>>(w, rng, off, (uint4*)wp);
    dim3 grid(32, 32);
    gemm_kernel<<<grid, 256, 0, stream>>>(yb, wp, out);
}

// Round 3
// 308.068 us; speedup vs baseline: 1.1135x; 1.0973x over previous
//
#include <hip/hip_runtime.h>

typedef unsigned short u16;
typedef unsigned int u32;

typedef __bf16 bf16x8 __attribute__((ext_vector_type(8)));
typedef float f32x4 __attribute__((ext_vector_type(4)));

__device__ inline u16 f2bf(float f) {
    u32 u = __float_as_uint(f);
    u32 r = u + 0x7fffu + ((u >> 16) & 1u);   // round-to-nearest-even
    return (u16)(r >> 16);
}
__device__ inline u32 pack2(float a, float b) {
    return (u32)f2bf(a) | ((u32)f2bf(b) << 16);
}

// Swizzled bf16 storage (yb and wp), BK=64 flavor:
// 16B unit at p = row*512 + t*8 + j (t = 64-k block) holds logical 8-elem
// chunk l = j ^ (row & 7), i.e. k = t*64 + l*8. With LDS row stride 128B,
// fragment ds_read_b128 then hits all 8 bank-groups 2x per 16-lane phase
// (2-way = free, m136).

// ---- prep 1: cast y (fp32 [M][K]) -> swizzled bf16, one 16B unit/thread ----
__global__ __launch_bounds__(256) void cast_y_kernel(const float* __restrict__ y,
                                                     uint4* __restrict__ yb) {
    int p = blockIdx.x * 256 + threadIdx.x;   // [0, 4096*512)
    int row = p >> 9;
    int c = p & 511;
    int t = c >> 3;
    int j = c & 7;
    int l = j ^ (row & 7);
    int kstart = t * 64 + l * 8;
    const float* src = y + (size_t)row * 4096 + kstart;
    float4 v0 = ((const float4*)src)[0];
    float4 v1 = ((const float4*)src)[1];
    uint4 o;
    o.x = pack2(v0.x, v0.y);
    o.y = pack2(v0.z, v0.w);
    o.z = pack2(v1.x, v1.y);
    o.w = pack2(v1.z, v1.w);
    yb[p] = o;
}

// ---- prep 2: Wp[n][k] = bf16(rng[k]*w[k][n] + off[k]), transposed + swizzled ----
__global__ __launch_bounds__(256) void make_wp_kernel(const float* __restrict__ w,
                                                      const float* __restrict__ rng,
                                                      const float* __restrict__ off,
                                                      uint4* __restrict__ wp) {
    __shared__ u16 tile[64][72];              // [k_local][n_local]
    const int n0 = (blockIdx.x & 63) * 64;
    const int k0 = (blockIdx.x >> 6) * 64;
    const int c4 = threadIdx.x & 15;          // float4 column
    const int r0 = threadIdx.x >> 4;          // 0..15
    #pragma unroll
    for (int i = 0; i < 4; ++i) {
        int kk = r0 + i * 16;
        int k = k0 + kk;
        float4 v = *(const float4*)&w[(size_t)k * 4096 + n0 + c4 * 4];  // 256B/wave rows
        float s = rng[k], o = off[k];
        u32 lo = pack2(s * v.x + o, s * v.y + o);
        u32 hi = pack2(s * v.z + o, s * v.w + o);
        *(uint2*)&tile[kk][c4 * 4] = make_uint2(lo, hi);   // ds_write_b64, 8B-aligned
    }
    __syncthreads();
    const int t8 = (k0 >> 6) * 8;
    #pragma unroll
    for (int h = 0; h < 2; ++h) {
        int nl = (threadIdx.x >> 3) + h * 32;
        int j = threadIdx.x & 7;
        int kl = (j ^ (nl & 7)) * 8;
        uint4 o;
        o.x = (u32)tile[kl + 0][nl] | ((u32)tile[kl + 1][nl] << 16);
        o.y = (u32)tile[kl + 2][nl] | ((u32)tile[kl + 3][nl] << 16);
        o.z = (u32)tile[kl + 4][nl] | ((u32)tile[kl + 5][nl] << 16);
        o.w = (u32)tile[kl + 6][nl] | ((u32)tile[kl + 7][nl] << 16);
        wp[(size_t)(n0 + nl) * 512 + t8 + j] = o;   // 16B/lane coalesced
    }
}

// ---- async global->LDS, 16B per lane; LDS dest = wave-uniform base + lane*16 ----
__device__ inline void gld16(const u16* g, u16* l) {
    __builtin_amdgcn_global_load_lds((const __attribute__((address_space(1))) void*)g,
                                     (__attribute__((address_space(3))) void*)l,
                                     16, 0, 0);
}

// ---- GEMM: out[m][n] = sum_k yb[m][k]*wp[n][k], swizzled bf16, BK=64 ----
// 128x128 tile, 4 waves (2x2), 64x64/wave via 4x4 MFMA 16x16x32, 32 MFMA/barrier-pair
__global__ __launch_bounds__(256) void gemm_kernel(const u16* __restrict__ yb,
                                                   const u16* __restrict__ wp,
                                                   float* __restrict__ out) {
    __shared__ u16 As[128 * 64];  // 16KB, flat copy of swizzled global
    __shared__ u16 Bs[128 * 64];  // 16KB
    // XCD swizzle: 8 XCDs round-robin on blockIdx; 4 bn-tiles per XCD (B slice = 4MB = L2)
    const int bid = blockIdx.x;
    const int xcd = bid & 7;
    const int jj = bid >> 3;                  // 0..127
    const int bn = (xcd * 4 + (jj & 3)) * 128;
    const int bm = (jj >> 2) * 128;

    const int lane = threadIdx.x & 63;
    const int wv = threadIdx.x >> 6;
    const int wm = (wv >> 1) * 64;
    const int wn = (wv & 1) * 64;
    const int r = lane & 15;
    const int q = lane >> 4;
    const int j0 = (q ^ (r & 7)) * 8;         // u16 offset of substep-0 chunk; s=1 -> ^32

    // staging: each tile = 16 chunks of 64 units (1KB); wave wv does chunks wv*4..wv*4+3
    const int rsub = lane >> 3;               // 0..7 rows within chunk
    const int jsub = lane & 7;                // unit within row
    const u16* gA[4]; const u16* gB[4]; u16* lA[4]; u16* lB[4];
    #pragma unroll
    for (int c = 0; c < 4; ++c) {
        int ca = wv * 4 + c;
        gA[c] = yb + (size_t)(bm + ca * 8 + rsub) * 4096 + jsub * 8;
        gB[c] = wp + (size_t)(bn + ca * 8 + rsub) * 4096 + jsub * 8;
        lA[c] = &As[ca * 512];
        lB[c] = &Bs[ca * 512];
    }

    f32x4 acc[4][4] = {};

    for (int kt = 0; kt < 64; ++kt) {
        #pragma unroll
        for (int c = 0; c < 4; ++c) {
            gld16(gA[c], lA[c]);
            gld16(gB[c], lB[c]);
            gA[c] += 64; gB[c] += 64;
        }
        __syncthreads();

        #pragma unroll
        for (int s = 0; s < 2; ++s) {
            const int js = j0 ^ (s * 32);
            bf16x8 af[4], bfr[4];
            #pragma unroll
            for (int i = 0; i < 4; ++i)
                af[i] = *(const bf16x8*)&As[(wm + i * 16 + r) * 64 + js];
            #pragma unroll
            for (int i = 0; i < 4; ++i)
                bfr[i] = *(const bf16x8*)&Bs[(wn + i * 16 + r) * 64 + js];
            #pragma unroll
            for (int i = 0; i < 4; ++i) {
                #pragma unroll
                for (int j = 0; j < 4; ++j)
                    acc[i][j] = __builtin_amdgcn_mfma_f32_16x16x32_bf16(af[i], bfr[j], acc[i][j], 0, 0, 0);
            }
        }
        __syncthreads();
    }

    // C/D layout: n = lane&15, m = (lane>>4)*4 + reg
    #pragma unroll
    for (int i = 0; i < 4; ++i) {
        const int gm = bm + wm + i * 16 + q * 4;
        #pragma unroll
        for (int j = 0; j < 4; ++j) {
            const int gn = bn + wn + j * 16 + r;
            float* op = out + (size_t)gm * 4096 + gn;
            #pragma unroll
            for (int rr = 0; rr < 4; ++rr)
                op[(size_t)rr * 4096] = acc[i][j][rr];
        }
    }
}

extern "C" void kernel_launch(void* const* d_in, const int* in_sizes, int n_in,
                              void* d_out, int out_size, void* d_ws, size_t ws_size,
                              hipStream_t stream) {
    const float* y   = (const float*)d_in[0];   // (B,T,C) = 2*2048*4096
    const float* w   = (const float*)d_in[1];   // (C,N)   = 4096*4096
    const float* rng = (const float*)d_in[2];   // (1,1,C) = 4096
    const float* off = (const float*)d_in[3];   // (C,)    = 4096
    float* out = (float*)d_out;                 // (B,T,N) fp32

    u16* yb = (u16*)d_ws;                       // 32MB swizzled bf16 [m][k]
    u16* wp = yb + (size_t)4096 * 4096;         // 32MB swizzled bf16 [n][k]

    cast_y_kernel<<<8192, 256, 0, stream>>>(y, (uint4*)yb);
    make_wp_kernel<<<4096, 256, 0, stream>>>(w, rng, off, (uint4*)wp);
    gemm_kernel<<<1024, 256, 0, stream>>>(yb, wp, out);
}

// Round 4
// 244.376 us; speedup vs baseline: 1.4037x; 1.2606x over previous
//
#include <hip/hip_runtime.h>

typedef unsigned short u16;
typedef unsigned int u32;
typedef unsigned char u8;
typedef signed char i8;

typedef int i32x4 __attribute__((ext_vector_type(4)));

// ---- prep 1: per-row i8 quantization of ysr = y*rng, plus row scalars ----
// qy unit p = row*256 + t*8 + j holds logical chunk l = j ^ (row&7) of
// 128-k block t (16 i8, k = t*128 + l*16). sp[m] = s_m/127,
// tv[m] = 128*sum_k(y*rng) + sum_k(y*off).
__global__ __launch_bounds__(256) void quant_y_kernel(const float* __restrict__ y,
                                                      const float* __restrict__ rng,
                                                      const float* __restrict__ off,
                                                      uint4* __restrict__ qy,
                                                      float* __restrict__ sp,
                                                      float* __restrict__ tv) {
    const int row = blockIdx.x;
    const int tid = threadIdx.x;
    const float* yr = y + (size_t)row * 4096;
    const int base = tid * 16;

    float ysr[16];
    float amax = 0.0f, s1 = 0.0f, s2 = 0.0f;
    #pragma unroll
    for (int ii = 0; ii < 4; ++ii) {
        float4 v = *(const float4*)&yr[base + ii * 4];
        float4 g = *(const float4*)&rng[base + ii * 4];
        float4 o = *(const float4*)&off[base + ii * 4];
        float p0 = v.x * g.x, p1 = v.y * g.y, p2 = v.z * g.z, p3 = v.w * g.w;
        ysr[ii * 4 + 0] = p0; ysr[ii * 4 + 1] = p1;
        ysr[ii * 4 + 2] = p2; ysr[ii * 4 + 3] = p3;
        s1 += p0 + p1 + p2 + p3;
        s2 += v.x * o.x + v.y * o.y + v.z * o.z + v.w * o.w;
        amax = fmaxf(amax, fmaxf(fmaxf(fabsf(p0), fabsf(p1)), fmaxf(fabsf(p2), fabsf(p3))));
    }
    #pragma unroll
    for (int d = 32; d > 0; d >>= 1) {
        amax = fmaxf(amax, __shfl_down(amax, d));
        s1 += __shfl_down(s1, d);
        s2 += __shfl_down(s2, d);
    }
    __shared__ float ra[4], rs1[4], rs2[4];
    const int wv = tid >> 6;
    if ((tid & 63) == 0) { ra[wv] = amax; rs1[wv] = s1; rs2[wv] = s2; }
    __syncthreads();
    const float sm = fmaxf(fmaxf(ra[0], ra[1]), fmaxf(ra[2], ra[3]));
    const float inv = sm > 0.0f ? 127.0f / sm : 0.0f;

    u32 d[4];
    #pragma unroll
    for (int g = 0; g < 4; ++g) {
        u32 b0 = (u8)(i8)(int)rintf(ysr[g * 4 + 0] * inv);
        u32 b1 = (u8)(i8)(int)rintf(ysr[g * 4 + 1] * inv);
        u32 b2 = (u8)(i8)(int)rintf(ysr[g * 4 + 2] * inv);
        u32 b3 = (u8)(i8)(int)rintf(ysr[g * 4 + 3] * inv);
        d[g] = b0 | (b1 << 8) | (b2 << 16) | (b3 << 24);
    }
    const int j = (tid & 7) ^ (row & 7);
    qy[(size_t)row * 256 + (tid >> 3) * 8 + j] = make_uint4(d[0], d[1], d[2], d[3]);
    if (tid == 0) {
        sp[row] = sm / 127.0f;
        tv[row] = 128.0f * (rs1[0] + rs1[1] + rs1[2] + rs1[3])
                        + (rs2[0] + rs2[1] + rs2[2] + rs2[3]);
    }
}

// ---- prep 2: wq[n][k] = (i8)(w[k][n] - 128), transposed + swizzled ----
__global__ __launch_bounds__(256) void quant_w_kernel(const float* __restrict__ w,
                                                      uint4* __restrict__ wq) {
    __shared__ i8 tile[64][68];               // [k_local][n_local], u32-aligned stride
    const int n0 = (blockIdx.x & 63) * 64;
    const int k0 = (blockIdx.x >> 6) * 64;
    const int c4 = threadIdx.x & 15;
    const int r0 = threadIdx.x >> 4;
    #pragma unroll
    for (int i = 0; i < 4; ++i) {
        int kk = r0 + i * 16;
        float4 v = *(const float4*)&w[(size_t)(k0 + kk) * 4096 + n0 + c4 * 4];
        u32 b0 = (u8)(i8)((int)v.x - 128);
        u32 b1 = (u8)(i8)((int)v.y - 128);
        u32 b2 = (u8)(i8)((int)v.z - 128);
        u32 b3 = (u8)(i8)((int)v.w - 128);
        *(u32*)&tile[kk][c4 * 4] = b0 | (b1 << 8) | (b2 << 16) | (b3 << 24);
    }
    __syncthreads();
    const int nl = threadIdx.x >> 2;          // 0..63
    const int ci = threadIdx.x & 3;           // 16-elem chunk within this 64-k tile
    const int l = ((k0 >> 4) & 7) + ci;       // logical chunk within 128-k block
    const int j = l ^ ((n0 + nl) & 7);
    u32 d[4];
    #pragma unroll
    for (int g = 0; g < 4; ++g) {
        int kl = ci * 16 + g * 4;
        d[g] = (u32)(u8)tile[kl + 0][nl] | ((u32)(u8)tile[kl + 1][nl] << 8)
             | ((u32)(u8)tile[kl + 2][nl] << 16) | ((u32)(u8)tile[kl + 3][nl] << 24);
    }
    wq[(size_t)(n0 + nl) * 256 + (k0 >> 7) * 8 + j] = make_uint4(d[0], d[1], d[2], d[3]);
}

// ---- async global->LDS, 16B per lane ----
__device__ inline void gld16(const i8* g, i8* l) {
    __builtin_amdgcn_global_load_lds((const __attribute__((address_space(1))) void*)g,
                                     (__attribute__((address_space(3))) void*)l,
                                     16, 0, 0);
}

// ---- GEMM: Q[m][n] = sum_k qy[m][k]*wq[n][k] (i8->i32 exact), BK=128 ----
// out[m][n] = sp[m]*Q + tv[m]. 128x128 tile, 4 waves, 4x4 MFMA 16x16x64 i8,
// 32 K-iterations (half of R3), 32 MFMA per barrier-pair.
__global__ __launch_bounds__(256) void gemm_kernel(const i8* __restrict__ qy,
                                                   const i8* __restrict__ wq,
                                                   const float* __restrict__ sp,
                                                   const float* __restrict__ tv,
                                                   float* __restrict__ out) {
    __shared__ i8 As[128 * 128];  // 16KB, flat copy of swizzled global
    __shared__ i8 Bs[128 * 128];  // 16KB
    const int bid = blockIdx.x;
    const int xcd = bid & 7;
    const int jj = bid >> 3;
    const int bn = (xcd * 4 + (jj & 3)) * 128;
    const int bm = (jj >> 2) * 128;

    const int lane = threadIdx.x & 63;
    const int wv = threadIdx.x >> 6;
    const int wm = (wv >> 1) * 64;
    const int wn = (wv & 1) * 64;
    const int r = lane & 15;
    const int q = lane >> 4;
    const int j0 = q ^ (r & 7);               // stored-unit index of substep-0 chunk

    // staging: tile = 16 chunks of 1KB (8 rows x 128B); wave wv does chunks wv*4..+3
    const int rsub = lane >> 3;
    const int jsub = lane & 7;
    const i8* gA[4]; const i8* gB[4]; i8* lA[4]; i8* lB[4];
    #pragma unroll
    for (int c = 0; c < 4; ++c) {
        int ca = wv * 4 + c;
        gA[c] = qy + (size_t)(bm + ca * 8 + rsub) * 4096 + jsub * 16;
        gB[c] = wq + (size_t)(bn + ca * 8 + rsub) * 4096 + jsub * 16;
        lA[c] = &As[ca * 1024];
        lB[c] = &Bs[ca * 1024];
    }

    i32x4 acc[4][4] = {};

    for (int kt = 0; kt < 32; ++kt) {
        #pragma unroll
        for (int c = 0; c < 4; ++c) {
            gld16(gA[c], lA[c]);
            gld16(gB[c], lB[c]);
            gA[c] += 128; gB[c] += 128;
        }
        __syncthreads();

        #pragma unroll
        for (int s = 0; s < 2; ++s) {
            const int js = (j0 ^ (s * 4)) * 16;   // byte offset of this lane's chunk
            i32x4 af[4], bfr[4];
            #pragma unroll
            for (int i = 0; i < 4; ++i)
                af[i] = *(const i32x4*)&As[(wm + i * 16 + r) * 128 + js];
            #pragma unroll
            for (int i = 0; i < 4; ++i)
                bfr[i] = *(const i32x4*)&Bs[(wn + i * 16 + r) * 128 + js];
            #pragma unroll
            for (int i = 0; i < 4; ++i) {
                #pragma unroll
                for (int j = 0; j < 4; ++j)
                    acc[i][j] = __builtin_amdgcn_mfma_i32_16x16x64_i8(af[i], bfr[j], acc[i][j], 0, 0, 0);
            }
        }
        __syncthreads();
    }

    // C/D layout: n = lane&15, m = (lane>>4)*4 + reg (dtype-independent, m121-128)
    #pragma unroll
    for (int i = 0; i < 4; ++i) {
        #pragma unroll
        for (int rr = 0; rr < 4; ++rr) {
            const int gm = bm + wm + i * 16 + q * 4 + rr;
            const float sc = sp[gm];
            const float tt = tv[gm];
            #pragma unroll
            for (int j = 0; j < 4; ++j) {
                const int gn = bn + wn + j * 16 + r;
                out[(size_t)gm * 4096 + gn] = sc * (float)acc[i][j][rr] + tt;
            }
        }
    }
}

extern "C" void kernel_launch(void* const* d_in, const int* in_sizes, int n_in,
                              void* d_out, int out_size, void* d_ws, size_t ws_size,
                              hipStream_t stream) {
    const float* y   = (const float*)d_in[0];   // (B,T,C) = 2*2048*4096
    const float* w   = (const float*)d_in[1];   // (C,N)   = 4096*4096
    const float* rng = (const float*)d_in[2];   // (1,1,C) = 4096
    const float* off = (const float*)d_in[3];   // (C,)    = 4096
    float* out = (float*)d_out;                 // (B,T,N) fp32

    i8* qy = (i8*)d_ws;                         // 16MB swizzled i8 [m][k]
    i8* wq = qy + (size_t)4096 * 4096;          // 16MB swizzled i8 [n][k]
    float* sp = (float*)(wq + (size_t)4096 * 4096);  // 16KB per-row scale
    float* tv = sp + 4096;                           // 16KB per-row additive term

    quant_y_kernel<<<4096, 256, 0, stream>>>(y, rng, off, (uint4*)qy, sp, tv);
    quant_w_kernel<<<4096, 256, 0, stream>>>(w, (uint4*)wq);
    gemm_kernel<<<1024, 256, 0, stream>>>(qy, wq, sp, tv, out);
}